// Round 6
// baseline (78.696 us; speedup 1.0000x reference)
//
#include <hip/hip_runtime.h>
#include <hip/hip_bf16.h>
#include <hip/hip_fp16.h>

#define A_NUM 128
#define U_NUM 8
#define ANT 64
#define D2 64
#define H_DIM 256
#define NUE 1024
#define E_INT 131072

typedef __attribute__((ext_vector_type(8))) short bf16x8_t;
typedef __attribute__((ext_vector_type(4))) float f32x4_t;

// round-to-nearest-even f32 -> bf16
static __device__ inline unsigned short f2bf(float x) {
    unsigned int u = __float_as_uint(x);
    unsigned int r = (u + 0x7fffu + ((u >> 16) & 1u)) >> 16;
    return (unsigned short)r;
}
static __device__ inline unsigned int pack2(float a, float b) {
    return (unsigned int)f2bf(a) | ((unsigned int)f2bf(b) << 16);
}
static __device__ inline float bf2f(unsigned short s) {
    return __uint_as_float(((unsigned int)s) << 16);
}

// ---------------------------------------------------------------------------
// Kernel A: prep. blocks 0..127: Sa[a,h]. blocks 128..135: WpT/W2bT bf16 pack.
// blocks 136..167: f32 transposes W1aT[256][208] (pad), W1bT[128][256]
// (coalesced reads, scattered writes).
// ---------------------------------------------------------------------------
__global__ void prep_kernel(const float* __restrict__ pv_re, const float* __restrict__ pv_im,
                            const float* __restrict__ W2a, const float* __restrict__ b2a,
                            const float* __restrict__ W2b,
                            const float* __restrict__ W1a, const float* __restrict__ W1b,
                            float* __restrict__ Sa, unsigned short* __restrict__ WpT,
                            unsigned short* __restrict__ W2bT,
                            float* __restrict__ W1aT, float* __restrict__ W1bT) {
    int bid = blockIdx.x, t = threadIdx.x;
    if (bid < A_NUM) {
        __shared__ float sre[ANT], sim[ANT];
        if (t < ANT) {
            float s = 0.f;
            for (int u = 0; u < U_NUM; ++u) s += pv_re[bid * 512 + u * 64 + t];
            sre[t] = s;
        } else if (t < 2 * ANT) {
            int ant = t - ANT;
            float s = 0.f;
            for (int u = 0; u < U_NUM; ++u) s += pv_im[bid * 512 + u * 64 + ant];
            sim[ant] = s;
        }
        __syncthreads();
        float a0 = 0.f, a1 = 0.f, a2 = 0.f, a3 = 0.f;
        for (int ant = 0; ant < ANT; ant += 2) {
            a0 += sre[ant] * W2a[(64 + ant) * H_DIM + t];
            a1 += sim[ant] * W2a[(192 + ant) * H_DIM + t];
            a2 += sre[ant + 1] * W2a[(64 + ant + 1) * H_DIM + t];
            a3 += sim[ant + 1] * W2a[(192 + ant + 1) * H_DIM + t];
        }
        Sa[bid * H_DIM + t] = b2a[t] + ((a0 + a2) + (a1 + a3));
    } else if (bid < 136) {
        int base = (bid - A_NUM) * 256 + t;
        for (int i = base; i < 32768 + 16384; i += 8 * 256) {
            if (i < 32768) {
                int h = i >> 7, k = i & 127;
                int row = (k < 64) ? k : (k + 64);
                WpT[i] = f2bf(W2a[row * H_DIM + h]);
            } else {
                int i2 = i - 32768;
                int d = i2 >> 8, k2 = i2 & 255;
                W2bT[i2] = f2bf(W2b[k2 * D2 + d]);
            }
        }
    } else {
        // coalesced reads: i enumerates (k,h) with h fastest
        for (int i = (bid - 136) * 256 + t; i < 53248 + 32768; i += 32 * 256) {
            if (i < 53248) {
                int k = i >> 8, h = i & 255;  // k 0..207, h 0..255
                W1aT[h * 208 + k] = (k < 193) ? W1a[k * 256 + h] : 0.f;
            } else {
                int i2 = i - 53248;
                int k = i2 >> 7, c = i2 & 127;  // k 0..255, c 0..127
                W1bT[c * 256 + k] = W1b[k * 128 + c];
            }
        }
    }
}

// ---------------------------------------------------------------------------
// Kernel B: big edge MLP via bf16 MFMA. Block = 16 j x 8 a, 256 thr, 1024
// blocks (4/CU). Weights register-hoisted (wave h-quarter / d-quarter);
// F double-buffered; 2 barriers/iter; partial written straight from acc2.
// ---------------------------------------------------------------------------
__global__ __launch_bounds__(256, 4) void mlp2_kernel(
        const float* __restrict__ plre, const float* __restrict__ plim,
        const float* __restrict__ Sa, const unsigned short* __restrict__ WpT,
        const unsigned short* __restrict__ W2bT, float* __restrict__ partial,
        unsigned short* __restrict__ Pws) {
    __shared__ __attribute__((aligned(16))) unsigned short F2[2][16 * 136];
    __shared__ __attribute__((aligned(16))) unsigned short Hl[16][264];
    int bid = blockIdx.x;
    int ac = bid >> 6, jt = bid & 63;
    int j0 = jt * 16, a0 = ac * 8;
    int t = threadIdx.x, w = t >> 6, l = t & 63, lm = l & 15, lk = l >> 4;

    // ---- register-hoisted weights ----
    bf16x8_t bfr[4][4];  // layer1 B: h = w*64 + ht*16 + lm
#pragma unroll
    for (int ht = 0; ht < 4; ++ht)
#pragma unroll
        for (int kc = 0; kc < 4; ++kc)
            bfr[ht][kc] = *reinterpret_cast<const bf16x8_t*>(
                WpT + (w * 64 + ht * 16 + lm) * 128 + kc * 32 + lk * 8);
    bf16x8_t b2h[8];     // layer2 B: d = w*16 + lm, k = kcl*32 + lk*8
#pragma unroll
    for (int kcl = 0; kcl < 8; ++kcl)
        b2h[kcl] = *reinterpret_cast<const bf16x8_t*>(
            W2bT + (w * 16 + lm) * 256 + kcl * 32 + lk * 8);

    // ---- staging identity: thread t -> (row er, 32B segment seg) ----
    int er = t >> 4, seg = t & 15;
    const float* stage_base = (seg < 8) ? plre : plim;
    int stage_off = (j0 + er) * 64 + (seg & 7) * 8;   // f32 index within row
    int fw = er * 136 + seg * 8;                      // u16 dest index in F

    f32x4_t acc2 = (f32x4_t){0.f, 0.f, 0.f, 0.f};

    float4 s0, s1;
    {   // stage iter 0 directly
        const float* p = stage_base + (size_t)a0 * 65536 + stage_off;
        s0 = *reinterpret_cast<const float4*>(p);
        s1 = *reinterpret_cast<const float4*>(p + 4);
        *reinterpret_cast<uint4*>(&F2[0][fw]) =
            make_uint4(pack2(s0.x, s0.y), pack2(s0.z, s0.w),
                       pack2(s1.x, s1.y), pack2(s1.z, s1.w));
    }
    {   // prefetch iter 1
        const float* p = stage_base + (size_t)(a0 + 1) * 65536 + stage_off;
        s0 = *reinterpret_cast<const float4*>(p);
        s1 = *reinterpret_cast<const float4*>(p + 4);
    }

    int cur = 0;
    for (int ai = 0; ai < 8; ++ai) {
        int a = a0 + ai;
        __syncthreads();  // A: F[cur] staged, Hl free
        const unsigned short* Fc = F2[cur];
        // ---- P emit (waves 0-1): P[e][ant] = re^2 + im^2 (fp16) ----
        if (t < 128) {
            int er3 = t >> 3, seg3 = t & 7;
            uint4 rr = *reinterpret_cast<const uint4*>(Fc + er3 * 136 + seg3 * 8);
            uint4 ri = *reinterpret_cast<const uint4*>(Fc + er3 * 136 + 64 + seg3 * 8);
            const unsigned short* pr = (const unsigned short*)&rr;
            const unsigned short* pi = (const unsigned short*)&ri;
            unsigned int pk[4];
#pragma unroll
            for (int i = 0; i < 4; ++i) {
                float re0 = bf2f(pr[2 * i]), im0 = bf2f(pi[2 * i]);
                float re1 = bf2f(pr[2 * i + 1]), im1 = bf2f(pi[2 * i + 1]);
                unsigned short h0 = __half_as_ushort(__float2half(re0 * re0 + im0 * im0));
                unsigned short h1 = __half_as_ushort(__float2half(re1 * re1 + im1 * im1));
                pk[i] = (unsigned int)h0 | ((unsigned int)h1 << 16);
            }
            *reinterpret_cast<uint4*>(&Pws[(unsigned)(a * 1024 + j0 + er3) * 64 + seg3 * 8]) =
                make_uint4(pk[0], pk[1], pk[2], pk[3]);
        }
        // ---- layer 1: D[16 j, h-quarter] ----
        f32x4_t acc1[4];
#pragma unroll
        for (int ht = 0; ht < 4; ++ht) {
            float sa = Sa[a * H_DIM + w * 64 + ht * 16 + lm];
            acc1[ht] = (f32x4_t){sa, sa, sa, sa};
        }
#pragma unroll
        for (int kc = 0; kc < 4; ++kc) {
            bf16x8_t afr = *reinterpret_cast<const bf16x8_t*>(Fc + lm * 136 + kc * 32 + lk * 8);
#pragma unroll
            for (int ht = 0; ht < 4; ++ht)
                acc1[ht] = __builtin_amdgcn_mfma_f32_16x16x32_bf16(afr, bfr[ht][kc], acc1[ht], 0, 0, 0);
        }
        // ---- relu -> bf16 -> Hl ----
#pragma unroll
        for (int ht = 0; ht < 4; ++ht)
#pragma unroll
            for (int r = 0; r < 4; ++r) {
                float v = acc1[ht][r];
                Hl[lk * 4 + r][ht * 16 + lm + w * 64] = f2bf(v > 0.f ? v : 0.f);
            }
        __syncthreads();  // B: Hl complete
        // ---- layer 2: wave's d-quarter, full K ----
#pragma unroll
        for (int kcl = 0; kcl < 8; ++kcl) {
            bf16x8_t a2 = *reinterpret_cast<const bf16x8_t*>(&Hl[lm][kcl * 32 + lk * 8]);
            acc2 = __builtin_amdgcn_mfma_f32_16x16x32_bf16(a2, b2h[kcl], acc2, 0, 0, 0);
        }
        // ---- stage next tile + issue loads for ai+2 ----
        if (ai < 7) {
            *reinterpret_cast<uint4*>(&F2[cur ^ 1][fw]) =
                make_uint4(pack2(s0.x, s0.y), pack2(s0.z, s0.w),
                           pack2(s1.x, s1.y), pack2(s1.z, s1.w));
            if (ai < 6) {
                const float* p = stage_base + (size_t)(a0 + ai + 2) * 65536 + stage_off;
                s0 = *reinterpret_cast<const float4*>(p);
                s1 = *reinterpret_cast<const float4*>(p + 4);
            }
            cur ^= 1;
        }
    }
    // ---- write per-chunk partial straight from acc2 ----
#pragma unroll
    for (int r = 0; r < 4; ++r)
        partial[ac * 65536 + (j0 + lk * 4 + r) * 64 + w * 16 + lm] = acc2[r];
}

// ---------------------------------------------------------------------------
// Kernel C: fused d-link MLP + per-AP normalization. One block per AP,
// 512 threads. Also folds the partial-chunk reduction for its 8 ue rows.
// ---------------------------------------------------------------------------
__global__ __launch_bounds__(512) void dlink_norm(
        const float* __restrict__ pv_re, const float* __restrict__ pv_im,
        const float* __restrict__ pldre, const float* __restrict__ pldim,
        const float* __restrict__ partial, const float* __restrict__ b2b,
        const float* __restrict__ W1aT, const float* __restrict__ b1a,
        const float* __restrict__ W1bT, const float* __restrict__ b1b,
        float* __restrict__ Q, float* __restrict__ out) {
    int a = blockIdx.x, t = threadIdx.x, w = t >> 6, l = t & 63;
    __shared__ float pvr[512], pvi[512], pldr[512], pldi[512];
    __shared__ float nrm[8][8];
    __shared__ __attribute__((aligned(16))) float feat[8][212];
    __shared__ __attribute__((aligned(16))) float h1[8][260];
    __shared__ float red2[2][8][128];
    __shared__ __attribute__((aligned(16))) float o1[8][128];
    __shared__ float redn[8];
    __shared__ float SshInv;

    pvr[t] = pv_re[a * 512 + t];
    pvi[t] = pv_im[a * 512 + t];
    pldr[t] = pldre[a * 512 + t];
    pldi[t] = pldim[a * 512 + t];
    {
        float acc = 128.f * b2b[t & 63];
#pragma unroll
        for (int c = 0; c < 16; ++c) acc += partial[c * 65536 + a * 512 + t];
        feat[t >> 6][129 + (t & 63)] = acc;
    }
    if (t < 152) feat[t / 19][193 + t % 19] = 0.f;
    __syncthreads();
    feat[t >> 6][1 + (t & 63)] = pldr[t];
    feat[t >> 6][65 + (t & 63)] = pldi[t];
#pragma unroll
    for (int p = 0; p < 8; ++p) {
        int idx = w * 8 + p;
        int el = idx >> 3, u = idx & 7;
        float pr = pvr[u * 64 + l], pi = pvi[u * 64 + l];
        float qr = pldr[el * 64 + l], qi = pldi[el * 64 + l];
        float ir = pr * qr + pi * qi;
        float ii = pr * qi - pi * qr;
        for (int m = 1; m < 64; m <<= 1) {
            ir += __shfl_xor(ir, m, 64);
            ii += __shfl_xor(ii, m, 64);
        }
        if (l == 0) nrm[el][u] = ir * ir + ii * ii;
    }
    __syncthreads();
    if (t < 8) {
        float s = 0.f;
        for (int u = 0; u < 8; ++u)
            if (u != t) s += nrm[t][u];
        feat[t][0] = s;
    }
    __syncthreads();
    {
        int h = t >> 1, e0 = (t & 1) * 4;
        const float4* wrow = reinterpret_cast<const float4*>(W1aT + h * 208);
        const float4* f0p = reinterpret_cast<const float4*>(&feat[e0 + 0][0]);
        const float4* f1p = reinterpret_cast<const float4*>(&feat[e0 + 1][0]);
        const float4* f2p = reinterpret_cast<const float4*>(&feat[e0 + 2][0]);
        const float4* f3p = reinterpret_cast<const float4*>(&feat[e0 + 3][0]);
        float ac0 = 0.f, ac1 = 0.f, ac2 = 0.f, ac3 = 0.f;
#pragma unroll 4
        for (int kq = 0; kq < 52; ++kq) {
            float4 wv = wrow[kq];
            float4 f0 = f0p[kq], f1 = f1p[kq], f2 = f2p[kq], f3 = f3p[kq];
            ac0 = fmaf(wv.x, f0.x, ac0); ac0 = fmaf(wv.y, f0.y, ac0);
            ac0 = fmaf(wv.z, f0.z, ac0); ac0 = fmaf(wv.w, f0.w, ac0);
            ac1 = fmaf(wv.x, f1.x, ac1); ac1 = fmaf(wv.y, f1.y, ac1);
            ac1 = fmaf(wv.z, f1.z, ac1); ac1 = fmaf(wv.w, f1.w, ac1);
            ac2 = fmaf(wv.x, f2.x, ac2); ac2 = fmaf(wv.y, f2.y, ac2);
            ac2 = fmaf(wv.z, f2.z, ac2); ac2 = fmaf(wv.w, f2.w, ac2);
            ac3 = fmaf(wv.x, f3.x, ac3); ac3 = fmaf(wv.y, f3.y, ac3);
            ac3 = fmaf(wv.z, f3.z, ac3); ac3 = fmaf(wv.w, f3.w, ac3);
        }
        float bb = b1a[h];
        float s0 = bb + ac0, s1 = bb + ac1, s2 = bb + ac2, s3 = bb + ac3;
        h1[e0 + 0][h] = s0 > 0.f ? s0 : 0.f;
        h1[e0 + 1][h] = s1 > 0.f ? s1 : 0.f;
        h1[e0 + 2][h] = s2 > 0.f ? s2 : 0.f;
        h1[e0 + 3][h] = s3 > 0.f ? s3 : 0.f;
    }
    __syncthreads();
    {
        int e0 = (t & 1) * 4, c = (t >> 1) & 127, kh = t >> 8;
        const float4* wrow = reinterpret_cast<const float4*>(W1bT + c * 256 + kh * 128);
        const float4* g0 = reinterpret_cast<const float4*>(&h1[e0 + 0][kh * 128]);
        const float4* g1 = reinterpret_cast<const float4*>(&h1[e0 + 1][kh * 128]);
        const float4* g2 = reinterpret_cast<const float4*>(&h1[e0 + 2][kh * 128]);
        const float4* g3 = reinterpret_cast<const float4*>(&h1[e0 + 3][kh * 128]);
        float ac0 = 0.f, ac1 = 0.f, ac2 = 0.f, ac3 = 0.f;
#pragma unroll 4
        for (int kq = 0; kq < 32; ++kq) {
            float4 wv = wrow[kq];
            float4 f0 = g0[kq], f1 = g1[kq], f2 = g2[kq], f3 = g3[kq];
            ac0 = fmaf(wv.x, f0.x, ac0); ac0 = fmaf(wv.y, f0.y, ac0);
            ac0 = fmaf(wv.z, f0.z, ac0); ac0 = fmaf(wv.w, f0.w, ac0);
            ac1 = fmaf(wv.x, f1.x, ac1); ac1 = fmaf(wv.y, f1.y, ac1);
            ac1 = fmaf(wv.z, f1.z, ac1); ac1 = fmaf(wv.w, f1.w, ac1);
            ac2 = fmaf(wv.x, f2.x, ac2); ac2 = fmaf(wv.y, f2.y, ac2);
            ac2 = fmaf(wv.z, f2.z, ac2); ac2 = fmaf(wv.w, f2.w, ac2);
            ac3 = fmaf(wv.x, f3.x, ac3); ac3 = fmaf(wv.y, f3.y, ac3);
            ac3 = fmaf(wv.z, f3.z, ac3); ac3 = fmaf(wv.w, f3.w, ac3);
        }
        red2[kh][e0 + 0][c] = ac0;
        red2[kh][e0 + 1][c] = ac1;
        red2[kh][e0 + 2][c] = ac2;
        red2[kh][e0 + 3][c] = ac3;
    }
    __syncthreads();
    {
        int i0 = t, i1 = t + 512;
        o1[i0 >> 7][i0 & 127] = b1b[i0 & 127] + red2[0][i0 >> 7][i0 & 127] + red2[1][i0 >> 7][i0 & 127];
        o1[i1 >> 7][i1 & 127] = b1b[i1 & 127] + red2[0][i1 >> 7][i1 & 127] + red2[1][i1 >> 7][i1 & 127];
    }
    __syncthreads();
    {
        int el = t >> 6, ant = t & 63;
        float re = o1[el][ant], im = o1[el][64 + ant];
        float v = sqrtf(re * re + im * im);
        for (int m = 1; m < 64; m <<= 1) v += __shfl_xor(v, m, 64);
        if (l == 0) redn[w] = v;
    }
    __syncthreads();
    if (t == 0) {
        float S = redn[0] + redn[1] + redn[2] + redn[3] +
                  redn[4] + redn[5] + redn[6] + redn[7];
        SshInv = 1.f / S;
    }
    __syncthreads();
    {
        float inv = SshInv;
        int el = t >> 6, ant = t & 63;
        out[a * 512 + t] = o1[el][ant] * inv;
        out[65536 + a * 512 + t] = o1[el][64 + ant] * inv;
        if (t < 64) {
            float sr = 0.f, si = 0.f;
#pragma unroll
            for (int u = 0; u < 8; ++u) {
                sr += o1[u][t];
                si += o1[u][64 + t];
            }
            sr *= inv;
            si *= inv;
            Q[a * 64 + t] = sr * sr + si * si;
        }
    }
}

// ---------------------------------------------------------------------------
// Kernel D: final aggregate from fp16 P (16.8 MB). One wave per j.
// ---------------------------------------------------------------------------
__global__ __launch_bounds__(256) void final_agg(const unsigned short* __restrict__ Pws,
                                                 const float* __restrict__ Qv,
                                                 float* __restrict__ out) {
    int bid = blockIdx.x, t = threadIdx.x, w = t >> 6, l = t & 63;
    __shared__ __attribute__((aligned(16))) float Qc[128][68];
    for (int i = t; i < 8192; i += 256) Qc[i >> 6][i & 63] = Qv[i];
    __syncthreads();
    int j = bid * 4 + w;
    int as = l >> 3, og = l & 7;
    float acc = 0.f;
#pragma unroll 4
    for (int ab = 0; ab < 16; ++ab) {
        int aa = ab * 8 + as;
        uint4 pv4 = *reinterpret_cast<const uint4*>(&Pws[(unsigned)(aa * 1024 + j) * 64 + og * 8]);
        float4 q0 = *reinterpret_cast<const float4*>(&Qc[aa][og * 8]);
        float4 q1 = *reinterpret_cast<const float4*>(&Qc[aa][og * 8 + 4]);
        const unsigned short* hp = (const unsigned short*)&pv4;
        acc += __half2float(__ushort_as_half(hp[0])) * q0.x;
        acc += __half2float(__ushort_as_half(hp[1])) * q0.y;
        acc += __half2float(__ushort_as_half(hp[2])) * q0.z;
        acc += __half2float(__ushort_as_half(hp[3])) * q0.w;
        acc += __half2float(__ushort_as_half(hp[4])) * q1.x;
        acc += __half2float(__ushort_as_half(hp[5])) * q1.y;
        acc += __half2float(__ushort_as_half(hp[6])) * q1.z;
        acc += __half2float(__ushort_as_half(hp[7])) * q1.w;
    }
    for (int m = 1; m < 64; m <<= 1) acc += __shfl_xor(acc, m, 64);
    if (l == 0) out[131072 + j] = acc;
}

extern "C" void kernel_launch(void* const* d_in, const int* in_sizes, int n_in,
                              void* d_out, int out_size, void* d_ws, size_t ws_size,
                              hipStream_t stream) {
    const float* plre = (const float*)d_in[0];
    const float* plim = (const float*)d_in[1];
    const float* pldre = (const float*)d_in[2];
    const float* pldim = (const float*)d_in[3];
    const float* pvre = (const float*)d_in[4];
    const float* pvim = (const float*)d_in[5];
    const float* W2a = (const float*)d_in[6];
    const float* b2a = (const float*)d_in[7];
    const float* W2b = (const float*)d_in[8];
    const float* b2b = (const float*)d_in[9];
    const float* W1a = (const float*)d_in[10];
    const float* b1a = (const float*)d_in[11];
    const float* W1b = (const float*)d_in[12];
    const float* b1b = (const float*)d_in[13];

    char* ws = (char*)d_ws;
    float* Sa = (float*)(ws);                               // 131072 B
    unsigned short* WpT = (unsigned short*)(ws + 131072);   // 65536 B
    unsigned short* W2bT = (unsigned short*)(ws + 196608);  // 32768 B
    float* Q = (float*)(ws + 229376);                       // 32768 B
    float* partial = (float*)(ws + 262144);                 // 4194304 B
    unsigned short* Pws = (unsigned short*)(ws + 4456448);  // 16777216 B
    float* W1aT = (float*)(ws + 21233664);                  // 212992 B
    float* W1bT = (float*)(ws + 21446656);                  // 131072 B
    float* out = (float*)d_out;

    prep_kernel<<<168, 256, 0, stream>>>(pvre, pvim, W2a, b2a, W2b, W1a, W1b,
                                         Sa, WpT, W2bT, W1aT, W1bT);
    mlp2_kernel<<<1024, 256, 0, stream>>>(plre, plim, Sa, WpT, W2bT, partial, Pws);
    dlink_norm<<<128, 512, 0, stream>>>(pvre, pvim, pldre, pldim, partial, b2b,
                                        W1aT, b1a, W1bT, b1b, Q, out);
    final_agg<<<256, 256, 0, stream>>>(Pws, Q, out);
}